// Round 4
// baseline (107987.134 us; speedup 1.0000x reference)
//
#include <hip/hip_runtime.h>
#include <hip/hip_bf16.h>

// LSTM: V=50000, E=512, H=512, S=16384, batch=1.
// Phase 1: gx[t][j][gate] = emb[x[t]] . W_ih + (b_ih+b_hh), bf16, layout [t][unit j][gate].
// Phase 2: 256 independent waves (32 wg x 8 waves), 2 hidden units per wave.
//          h exchanged as (f32,h tag) packed u64 atomics — no fences, no flags, no barriers.
// Phase 3: head MLP on wg 0 after the recurrence.

#define S_LEN 16384
#define HID   512
#define NWG   32
#define NTHR  512     // 8 waves per wg

typedef unsigned long long u64;

static __device__ __forceinline__ float bf2f(unsigned short u) {
  union { unsigned int i; float f; } v; v.i = ((unsigned int)u) << 16; return v.f;
}
static __device__ __forceinline__ unsigned short f2bf(float f) {
  union { float f; unsigned int i; } v; v.f = f;
  unsigned int r = v.i + 0x7fffu + ((v.i >> 16) & 1u);
  return (unsigned short)(r >> 16);
}
static __device__ __forceinline__ float fsig(float x) { return 1.f / (1.f + __expf(-x)); }
static __device__ __forceinline__ float ftanh(float x) { return 2.f / (1.f + __expf(-2.f * x)) - 1.f; }

// slot layout for h words: slot(k) = (k&7)*64 + (k>>3)
// => reader lane l, load i: k = l*8+i  lives at slot i*64 + l  (coalesced per load i)
static __device__ __forceinline__ int hslot(int k) { return (k & 7) * 64 + (k >> 3); }

// ---------------- Phase 1: gx GEMM ----------------
__global__ __launch_bounds__(256, 2) void gx_gemm(
    const int* __restrict__ x, const float* __restrict__ emb,
    const float* __restrict__ W_ih, const float* __restrict__ b_ih,
    const float* __restrict__ b_hh, unsigned short* __restrict__ gx)
{
  __shared__ float As[64][40];
  __shared__ float Bs[64][40];
  __shared__ int   xs[64];

  const int tid = threadIdx.x;
  const int bm = blockIdx.x;   // t tile
  const int bn = blockIdx.y;   // c tile

  if (tid < 64) xs[tid] = x[bm * 64 + tid];
  __syncthreads();

  float acc[4][4] = {};
  const int r0 = (tid >> 4) * 4;
  const int c0 = tid & 15;

  for (int kc = 0; kc < 512; kc += 32) {
#pragma unroll
    for (int h = 0; h < 2; ++h) {
      const int v = tid + h * 256;
      const int row = v >> 3, k4 = v & 7;
      const float4 av = *(const float4*)(emb + (size_t)xs[row] * 512 + kc + k4 * 4);
      As[row][k4 * 4 + 0] = av.x; As[row][k4 * 4 + 1] = av.y;
      As[row][k4 * 4 + 2] = av.z; As[row][k4 * 4 + 3] = av.w;
      const float4 bv = *(const float4*)(W_ih + (size_t)(bn * 64 + row) * 512 + kc + k4 * 4);
      Bs[row][k4 * 4 + 0] = bv.x; Bs[row][k4 * 4 + 1] = bv.y;
      Bs[row][k4 * 4 + 2] = bv.z; Bs[row][k4 * 4 + 3] = bv.w;
    }
    __syncthreads();
#pragma unroll
    for (int k4 = 0; k4 < 8; ++k4) {
      float4 a[4], b[4];
#pragma unroll
      for (int i = 0; i < 4; ++i) a[i] = *(const float4*)&As[r0 + i][k4 * 4];
#pragma unroll
      for (int j = 0; j < 4; ++j) b[j] = *(const float4*)&Bs[c0 + j * 16][k4 * 4];
#pragma unroll
      for (int i = 0; i < 4; ++i)
#pragma unroll
        for (int j = 0; j < 4; ++j) {
          acc[i][j] = __builtin_fmaf(a[i].x, b[j].x, acc[i][j]);
          acc[i][j] = __builtin_fmaf(a[i].y, b[j].y, acc[i][j]);
          acc[i][j] = __builtin_fmaf(a[i].z, b[j].z, acc[i][j]);
          acc[i][j] = __builtin_fmaf(a[i].w, b[j].w, acc[i][j]);
        }
    }
    __syncthreads();
  }

  // store layout [t][j][gate]: dst = t*2048 + j*4 + gate, j = c&511, gate = c>>9
#pragma unroll
  for (int j = 0; j < 4; ++j) {
    const int c = bn * 64 + c0 + j * 16;
    const float bias = b_ih[c] + b_hh[c];
    const size_t dstc = (size_t)(c & 511) * 4 + (size_t)(c >> 9);
#pragma unroll
    for (int i = 0; i < 4; ++i) {
      const size_t t = (size_t)bm * 64 + r0 + i;
      gx[t * 2048 + dstc] = f2bf(acc[i][j] + bias);
    }
  }
}

// ---------------- Phase 2: free-running dataflow recurrence ----------------
__global__ __launch_bounds__(NTHR, 2) void lstm_rec(
    const float* __restrict__ W_hh, const unsigned short* __restrict__ gx,
    const float* __restrict__ W1, const float* __restrict__ b1,
    const float* __restrict__ W2, const float* __restrict__ b2,
    float* __restrict__ out,
    u64* __restrict__ h_glob)   // [2][512] packed (f32 h, u32 tag)
{
  const int tid  = threadIdx.x;
  const int wave = blockIdx.x * (NTHR / 64) + (tid >> 6);  // 0..255
  const int lane = tid & 63;
  const int j0   = wave * 2;            // this wave owns units j0, j0+1

  // weights: wreg[rp][i], rp = (unit-j0)*4 + gate, lane's K = lane*8 + i
  float wreg[8][8];
#pragma unroll
  for (int rp = 0; rp < 8; ++rp) {
    const int unit = j0 + (rp >> 2);
    const int gate = rp & 3;
    const float* src = W_hh + ((size_t)(gate * 512 + unit)) * 512 + lane * 8;
    const float4 a = *(const float4*)(src);
    const float4 b = *(const float4*)(src + 4);
    wreg[rp][0] = a.x; wreg[rp][1] = a.y; wreg[rp][2] = a.z; wreg[rp][3] = a.w;
    wreg[rp][4] = b.x; wreg[rp][5] = b.y; wreg[rp][6] = b.z; wreg[rp][7] = b.w;
  }

  float h_reg[8];
#pragma unroll
  for (int i = 0; i < 8; ++i) h_reg[i] = 0.f;
  float c_reg = 0.f;                    // lanes 0,1 only
  const int myunit = j0 + (lane & 1);   // unit for gate lanes

  // gx prefetch (lanes 0,1), pipeline depth 2: ushort4 = 4 gates of myunit
  ushort4 g_cur = {0,0,0,0}, g_nxt = {0,0,0,0};
  if (lane < 2) {
    g_cur = *(const ushort4*)(gx + (size_t)0 * 2048 + myunit * 4);
    g_nxt = *(const ushort4*)(gx + (size_t)1 * 2048 + myunit * 4);
  }

  // publish slots for this wave's two units
  const int pslot = hslot(myunit);      // lane 0 -> j0, lane 1 -> j0+1

  for (int t = 0; t < S_LEN; ++t) {
    ushort4 g_new = {0,0,0,0};
    if (lane < 2 && t + 2 < S_LEN)
      g_new = *(const ushort4*)(gx + (size_t)(t + 2) * 2048 + myunit * 4);

    // partial dots: acc[rp] = sum_i wreg[rp][i] * h[lane*8+i]
    float acc[8];
#pragma unroll
    for (int rp = 0; rp < 8; ++rp) {
      float a = 0.f;
#pragma unroll
      for (int i = 0; i < 8; ++i) a = __builtin_fmaf(wreg[rp][i], h_reg[i], a);
      acc[rp] = a;
    }
    // butterfly over all 64 lanes
#pragma unroll
    for (int rp = 0; rp < 8; ++rp) {
      float a = acc[rp];
      a += __shfl_xor(a, 1);
      a += __shfl_xor(a, 2);
      a += __shfl_xor(a, 4);
      a += __shfl_xor(a, 8);
      a += __shfl_xor(a, 16);
      a += __shfl_xor(a, 32);
      acc[rp] = a;
    }

    // gates on lanes 0 (unit j0: acc[0..3]) and 1 (unit j0+1: acc[4..7])
    const float si = (lane == 0) ? acc[0] : acc[4];
    const float sf = (lane == 0) ? acc[1] : acc[5];
    const float sg = (lane == 0) ? acc[2] : acc[6];
    const float so = (lane == 0) ? acc[3] : acc[7];
    const float pi = si + bf2f(g_cur.x);
    const float pf = sf + bf2f(g_cur.y);
    const float pg = sg + bf2f(g_cur.z);
    const float po = so + bf2f(g_cur.w);
    const float ig = fsig(pi), fg = fsig(pf), gg = ftanh(pg), og = fsig(po);
    c_reg = fg * c_reg + ig * gg;
    const float hv = og * ftanh(c_reg);

    const int buf = (t + 1) & 1;
    if (lane < 2) {
      union { float f; unsigned int u; } hu; hu.f = hv;
      const u64 word = ((u64)(unsigned)(t + 1) << 32) | (u64)hu.u;
      __hip_atomic_store(&h_glob[buf * 512 + pslot], word,
                         __ATOMIC_RELAXED, __HIP_MEMORY_SCOPE_AGENT);
    }

    // poll h_{t+1}: lane l needs k = l*8+i at slot i*64+l (coalesced per i)
    if (t + 1 < S_LEN) {
      const u64* hb = h_glob + buf * 512;
      const unsigned want = (unsigned)(t + 1);
      u64 v[8];
      bool stale;
      do {
#pragma unroll
        for (int i = 0; i < 8; ++i)
          v[i] = __hip_atomic_load(&hb[i * 64 + lane],
                                   __ATOMIC_RELAXED, __HIP_MEMORY_SCOPE_AGENT);
        bool ok = true;
#pragma unroll
        for (int i = 0; i < 8; ++i) ok &= ((unsigned)(v[i] >> 32) == want);
        stale = !ok;
      } while (__any(stale));
#pragma unroll
      for (int i = 0; i < 8; ++i) {
        union { unsigned int u; float f; } hu; hu.u = (unsigned)v[i];
        h_reg[i] = hu.f;
      }
    }

    g_cur = g_nxt; g_nxt = g_new;
  }

  // ---------------- Phase 3: head (wg 0) ----------------
  if (blockIdx.x == 0) {
    __shared__ float hl[512];
    __shared__ float zl[128];
    {
      // final h_S lives in buf 0 (S even) with tag S
      const u64* hb = h_glob;  // buf 0
      const int slot = hslot(tid);
      u64 v;
      do {
        v = __hip_atomic_load(&hb[slot], __ATOMIC_RELAXED, __HIP_MEMORY_SCOPE_AGENT);
      } while ((unsigned)(v >> 32) != (unsigned)S_LEN);
      union { unsigned int u; float f; } hu; hu.u = (unsigned)v;
      hl[tid] = hu.f;
    }
    __syncthreads();
    // W1: 128 rows x 512 K; 4 threads per row
    const int j = tid >> 2, q = tid & 3;
    float sum = 0.f;
    const float4* w1v = (const float4*)(W1 + (size_t)j * 512 + q * 128);
#pragma unroll 8
    for (int k4 = 0; k4 < 32; ++k4) {
      const float4 v = w1v[k4];
      const int kb = q * 128 + k4 * 4;
      sum = __builtin_fmaf(v.x, hl[kb + 0], sum);
      sum = __builtin_fmaf(v.y, hl[kb + 1], sum);
      sum = __builtin_fmaf(v.z, hl[kb + 2], sum);
      sum = __builtin_fmaf(v.w, hl[kb + 3], sum);
    }
    sum += __shfl_xor(sum, 1);
    sum += __shfl_xor(sum, 2);
    if (q == 0) zl[j] = fsig(sum + b1[j]);
    __syncthreads();
    if (tid < 9) {
      float o = b2[tid];
      const float* w2r = W2 + tid * 128;
#pragma unroll 16
      for (int k = 0; k < 128; ++k) o = __builtin_fmaf(w2r[k], zl[k], o);
      out[tid] = fsig(o);
    }
  }
}

extern "C" void kernel_launch(void* const* d_in, const int* in_sizes, int n_in,
                              void* d_out, int out_size, void* d_ws, size_t ws_size,
                              hipStream_t stream) {
  const int*   x     = (const int*)d_in[0];
  const float* emb   = (const float*)d_in[1];
  const float* W_ih  = (const float*)d_in[2];
  const float* W_hh  = (const float*)d_in[3];
  const float* b_ih  = (const float*)d_in[4];
  const float* b_hh  = (const float*)d_in[5];
  const float* W1    = (const float*)d_in[6];
  const float* b1    = (const float*)d_in[7];
  const float* W2    = (const float*)d_in[8];
  const float* b2    = (const float*)d_in[9];
  float* out = (float*)d_out;

  const size_t gx_bytes = (size_t)S_LEN * 2048 * sizeof(unsigned short); // 64 MB
  const size_t h_off    = gx_bytes;
  if (ws_size < h_off + 2 * 512 * sizeof(u64)) return;  // fail visibly

  unsigned short* gxp    = (unsigned short*)d_ws;
  u64*            h_glob = (u64*)((char*)d_ws + h_off);

  // tags must be reset every launch (graph replays do not re-poison d_ws)
  (void)hipMemsetAsync(h_glob, 0, 2 * 512 * sizeof(u64), stream);

  dim3 g1(S_LEN / 64, 2048 / 64);
  gx_gemm<<<g1, 256, 0, stream>>>(x, emb, W_ih, b_ih, b_hh, gxp);
  lstm_rec<<<NWG, NTHR, 0, stream>>>(W_hh, gxp, W1, b1, W2, b2, out, h_glob);
}